// Round 1
// baseline (1970.640 us; speedup 1.0000x reference)
//
#include <hip/hip_runtime.h>

// d_out layout (fp32 elements): [out 8M][attn 128M][k 8M][v 8M]
#define ATT_OFF  (8ull * 1048576ull)
#define K_OFF    (136ull * 1048576ull)
#define V_OFF    (144ull * 1048576ull)

// ============================================================
// GEMM: C[M,N] = A[M,K] @ B[N,K]^T + bias, fp32
// BM=BN=128, BK=16, 256 threads, 8x8 micro-tile
// MODE 0: plain write Cout[row*N+col]
// MODE 1: qkv routing (N=3072): cols [0,1024)->Cout (q scratch in out region),
//         [1024,2048)->Cout+K_OFF, [2048,3072)->Cout+V_OFF, ldc=1024
// ============================================================
template<int MODE>
__global__ __launch_bounds__(256)
void gemm_bt(const float* __restrict__ A, const float* __restrict__ Bw,
             const float* __restrict__ bias, float* __restrict__ Cout,
             int M, int N, int K)
{
    __shared__ float As[16][128];
    __shared__ float Bs[16][128];
    const int tid = threadIdx.x;
    const int tx = tid & 15, ty = tid >> 4;
    const int m0 = blockIdx.y << 7, n0 = blockIdx.x << 7;
    const int lrow = tid >> 2;          // 0..63
    const int lk   = (tid & 3) << 2;    // 0,4,8,12

    float acc[8][8];
#pragma unroll
    for (int i = 0; i < 8; ++i)
#pragma unroll
        for (int j = 0; j < 8; ++j) acc[i][j] = 0.f;

    const float* pA0 = A  + (size_t)(m0 + lrow) * K + lk;
    const float* pA1 = A  + (size_t)(m0 + lrow + 64) * K + lk;
    const float* pB0 = Bw + (size_t)(n0 + lrow) * K + lk;
    const float* pB1 = Bw + (size_t)(n0 + lrow + 64) * K + lk;

    for (int k0 = 0; k0 < K; k0 += 16) {
        const float4 a0 = *(const float4*)(pA0 + k0);
        const float4 a1 = *(const float4*)(pA1 + k0);
        const float4 b0 = *(const float4*)(pB0 + k0);
        const float4 b1 = *(const float4*)(pB1 + k0);
        __syncthreads();
        As[lk+0][lrow]    = a0.x; As[lk+1][lrow]    = a0.y; As[lk+2][lrow]    = a0.z; As[lk+3][lrow]    = a0.w;
        As[lk+0][lrow+64] = a1.x; As[lk+1][lrow+64] = a1.y; As[lk+2][lrow+64] = a1.z; As[lk+3][lrow+64] = a1.w;
        Bs[lk+0][lrow]    = b0.x; Bs[lk+1][lrow]    = b0.y; Bs[lk+2][lrow]    = b0.z; Bs[lk+3][lrow]    = b0.w;
        Bs[lk+0][lrow+64] = b1.x; Bs[lk+1][lrow+64] = b1.y; Bs[lk+2][lrow+64] = b1.z; Bs[lk+3][lrow+64] = b1.w;
        __syncthreads();
#pragma unroll
        for (int kk = 0; kk < 16; ++kk) {
            const float4 av0 = *(const float4*)&As[kk][ty << 3];
            const float4 av1 = *(const float4*)&As[kk][(ty << 3) + 4];
            const float4 bv0 = *(const float4*)&Bs[kk][tx << 3];
            const float4 bv1 = *(const float4*)&Bs[kk][(tx << 3) + 4];
            const float am[8] = {av0.x, av0.y, av0.z, av0.w, av1.x, av1.y, av1.z, av1.w};
            const float bn[8] = {bv0.x, bv0.y, bv0.z, bv0.w, bv1.x, bv1.y, bv1.z, bv1.w};
#pragma unroll
            for (int i = 0; i < 8; ++i)
#pragma unroll
                for (int j = 0; j < 8; ++j)
                    acc[i][j] = __builtin_fmaf(am[i], bn[j], acc[i][j]);
        }
    }

    const int c0 = n0 + (tx << 3);
    const float4 bb0 = *(const float4*)&bias[c0];
    const float4 bb1 = *(const float4*)&bias[c0 + 4];
    const float bc[8] = {bb0.x, bb0.y, bb0.z, bb0.w, bb1.x, bb1.y, bb1.z, bb1.w};

    float* dst;
    int ldc, ccol;
    if (MODE == 1) {
        const int reg = n0 >> 10;   // uniform per block (128 | 1024)
        dst = Cout + (reg == 0 ? 0ull : (reg == 1 ? K_OFF : V_OFF));
        ldc = 1024;
        ccol = c0 - (reg << 10);
    } else {
        dst = Cout; ldc = N; ccol = c0;
    }
#pragma unroll
    for (int i = 0; i < 8; ++i) {
        const size_t row = (size_t)(m0 + (ty << 3) + i);
        float4 w0, w1;
        w0.x = acc[i][0] + bc[0]; w0.y = acc[i][1] + bc[1]; w0.z = acc[i][2] + bc[2]; w0.w = acc[i][3] + bc[3];
        w1.x = acc[i][4] + bc[4]; w1.y = acc[i][5] + bc[5]; w1.z = acc[i][6] + bc[6]; w1.w = acc[i][7] + bc[7];
        *(float4*)&dst[row * ldc + ccol]     = w0;
        *(float4*)&dst[row * ldc + ccol + 4] = w1;
    }
}

// ============================================================
// K2a: scores + exp + row sums.  Scrambled-head mapping:
//   Q[n,i,d] = qbuf[(i*8 + (n>>4))*1024 + (n&15)*64 + d]
// Per block: one n, 64 rows. Writes UNNORMALIZED E = exp(s/32 + mask)
// to attn region; row sums to ws. (scores ~N(0,0.08): no max-sub needed)
// ============================================================
__global__ __launch_bounds__(256)
void attn_scores(const float* __restrict__ qbuf, const float* __restrict__ kbuf,
                 const float* __restrict__ mask, float* __restrict__ attnE,
                 float* __restrict__ rowsum)
{
    __shared__ float QsT[64][68];    // [d][row]
    __shared__ float KsT[64][132];   // [d][j]  (j-tile = 128)
    __shared__ float red[64][17];
    const int tid = threadIdx.x;
    const int tx = tid & 15, ty = tid >> 4;
    const int n = blockIdx.y;
    const int i0 = blockIdx.x << 6;
    const int bidx = n >> 4;
    const int fc = (n & 15) << 6;

    // Q tile (64 rows x 64 d) -> transposed
#pragma unroll
    for (int s = 0; s < 4; ++s) {
        const int q = (tid << 2) + s;        // 0..1023
        const int row = q >> 4;              // 0..63
        const int dq = (q & 15) << 2;
        const float4 v = *(const float4*)&qbuf[((size_t)((i0 + row) << 3) + bidx) * 1024 + fc + dq];
        QsT[dq + 0][row] = v.x; QsT[dq + 1][row] = v.y; QsT[dq + 2][row] = v.z; QsT[dq + 3][row] = v.w;
    }

    const int r0 = ty << 2;   // 4 rows per thread
    const int cc = tx << 3;   // 8 cols per thread
    float rs[4] = {0.f, 0.f, 0.f, 0.f};
    const float sc = 0.03125f;  // 1/sqrt(E) = 1/32

    for (int j0 = 0; j0 < 1024; j0 += 128) {
        __syncthreads();
        // K tile (128 rows x 64 d) -> transposed KsT[d][j]
#pragma unroll
        for (int s = 0; s < 8; ++s) {
            const int q = (tid << 3) + s;    // 0..2047
            const int j = q >> 4;            // 0..127
            const int dq = (q & 15) << 2;
            const float4 v = *(const float4*)&kbuf[((size_t)((j0 + j) << 3) + bidx) * 1024 + fc + dq];
            KsT[dq + 0][j] = v.x; KsT[dq + 1][j] = v.y; KsT[dq + 2][j] = v.z; KsT[dq + 3][j] = v.w;
        }
        __syncthreads();

        float a[4][8];
#pragma unroll
        for (int i = 0; i < 4; ++i)
#pragma unroll
            for (int j = 0; j < 8; ++j) a[i][j] = 0.f;

#pragma unroll 8
        for (int d = 0; d < 64; ++d) {
            const float4 qv  = *(const float4*)&QsT[d][r0];
            const float4 k0v = *(const float4*)&KsT[d][cc];
            const float4 k1v = *(const float4*)&KsT[d][cc + 4];
            const float qq[4] = {qv.x, qv.y, qv.z, qv.w};
            const float kk[8] = {k0v.x, k0v.y, k0v.z, k0v.w, k1v.x, k1v.y, k1v.z, k1v.w};
#pragma unroll
            for (int i = 0; i < 4; ++i)
#pragma unroll
                for (int j = 0; j < 8; ++j)
                    a[i][j] = __builtin_fmaf(qq[i], kk[j], a[i][j]);
        }

#pragma unroll
        for (int i = 0; i < 4; ++i) {
            const size_t mrow = (size_t)bidx * 1048576ull + (size_t)(i0 + r0 + i) * 1024 + j0 + cc;
            const float4 m0v = *(const float4*)&mask[mrow];
            const float4 m1v = *(const float4*)&mask[mrow + 4];
            float4 e0, e1;
            e0.x = __expf(__builtin_fmaf(a[i][0], sc, m0v.x));
            e0.y = __expf(__builtin_fmaf(a[i][1], sc, m0v.y));
            e0.z = __expf(__builtin_fmaf(a[i][2], sc, m0v.z));
            e0.w = __expf(__builtin_fmaf(a[i][3], sc, m0v.w));
            e1.x = __expf(__builtin_fmaf(a[i][4], sc, m1v.x));
            e1.y = __expf(__builtin_fmaf(a[i][5], sc, m1v.y));
            e1.z = __expf(__builtin_fmaf(a[i][6], sc, m1v.z));
            e1.w = __expf(__builtin_fmaf(a[i][7], sc, m1v.w));
            const size_t arow = (size_t)n * 1048576ull + (size_t)(i0 + r0 + i) * 1024 + j0 + cc;
            *(float4*)&attnE[arow]     = e0;
            *(float4*)&attnE[arow + 4] = e1;
            rs[i] += e0.x + e0.y + e0.z + e0.w + e1.x + e1.y + e1.z + e1.w;
        }
    }

    __syncthreads();
#pragma unroll
    for (int i = 0; i < 4; ++i) red[r0 + i][tx] = rs[i];
    __syncthreads();
    if (tid < 64) {
        float s = 0.f;
#pragma unroll
        for (int x = 0; x < 16; ++x) s += red[tid][x];
        rowsum[(size_t)n * 1024 + i0 + tid] = s;
    }
}

// ============================================================
// K2b: normalize attn in place (final output) + PV -> ctx (scrambled layout)
// ============================================================
__global__ __launch_bounds__(256)
void attn_pv(float* __restrict__ attnP, const float* __restrict__ vbuf,
             const float* __restrict__ rowsum, float* __restrict__ ctx)
{
    __shared__ float PsT[64][68];   // [j][row]
    __shared__ float Vs[64][68];    // [j][d]
    __shared__ float invs[64];
    const int tid = threadIdx.x;
    const int tx = tid & 15, ty = tid >> 4;
    const int n = blockIdx.y;
    const int i0 = blockIdx.x << 6;
    const int bidx = n >> 4;
    const int fc = (n & 15) << 6;

    if (tid < 64) invs[tid] = 1.0f / rowsum[(size_t)n * 1024 + i0 + tid];

    const int r0 = ty << 2;   // 4 rows
    const int dc = tx << 2;   // 4 d-cols
    float acc[4][4];
#pragma unroll
    for (int i = 0; i < 4; ++i)
#pragma unroll
        for (int j = 0; j < 4; ++j) acc[i][j] = 0.f;

    for (int j0 = 0; j0 < 1024; j0 += 64) {
        __syncthreads();
        // stage P tile: read E, normalize, write back (final attn), LDS transposed
#pragma unroll
        for (int s = 0; s < 4; ++s) {
            const int q = (tid << 2) + s;
            const int row = q >> 4;
            const int cq = (q & 15) << 2;
            const size_t g = (size_t)n * 1048576ull + (size_t)(i0 + row) * 1024 + j0 + cq;
            float4 e = *(const float4*)&attnP[g];
            const float iv = invs[row];
            e.x *= iv; e.y *= iv; e.z *= iv; e.w *= iv;
            *(float4*)&attnP[g] = e;
            PsT[cq + 0][row] = e.x; PsT[cq + 1][row] = e.y; PsT[cq + 2][row] = e.z; PsT[cq + 3][row] = e.w;
        }
        // stage V tile (natural [j][d])
#pragma unroll
        for (int s = 0; s < 4; ++s) {
            const int q = (tid << 2) + s;
            const int j = q >> 4;
            const int dq = (q & 15) << 2;
            const float4 v = *(const float4*)&vbuf[((size_t)((j0 + j) << 3) + bidx) * 1024 + fc + dq];
            *(float4*)&Vs[j][dq] = v;
        }
        __syncthreads();

#pragma unroll 8
        for (int jj = 0; jj < 64; ++jj) {
            const float4 pv = *(const float4*)&PsT[jj][r0];
            const float4 vv = *(const float4*)&Vs[jj][dc];
            const float pp[4] = {pv.x, pv.y, pv.z, pv.w};
            const float vl[4] = {vv.x, vv.y, vv.z, vv.w};
#pragma unroll
            for (int i = 0; i < 4; ++i)
#pragma unroll
                for (int j = 0; j < 4; ++j)
                    acc[i][j] = __builtin_fmaf(pp[i], vl[j], acc[i][j]);
        }
    }

    // ctx[(i*8 + b)*1024 + (n&15)*64 + d]  (inverse split-heads)
#pragma unroll
    for (int i = 0; i < 4; ++i) {
        const size_t g = ((size_t)((i0 + r0 + i) << 3) + bidx) * 1024 + fc + dc;
        float4 o;
        o.x = acc[i][0]; o.y = acc[i][1]; o.z = acc[i][2]; o.w = acc[i][3];
        *(float4*)&ctx[g] = o;
    }
}

extern "C" void kernel_launch(void* const* d_in, const int* in_sizes, int n_in,
                              void* d_out_v, int out_size, void* d_ws, size_t ws_size,
                              hipStream_t stream)
{
    const float* query = (const float*)d_in[0];
    // d_in[1] (key), d_in[2] (value) are unused by the reference (self-attn from query)
    const float* mask  = (const float*)d_in[3];
    const float* qkv_w = (const float*)d_in[4];
    const float* qkv_b = (const float*)d_in[5];
    const float* out_w = (const float*)d_in[6];
    const float* out_b = (const float*)d_in[7];
    float* d_out = (float*)d_out_v;

    float* ctx    = (float*)d_ws;                        // 8M floats (32 MB)
    float* rowsum = (float*)d_ws + 8ull * 1048576ull;    // 128K floats

    // K1: qkv projection; q -> d_out[0:8M) (scratch until K3), k/v -> final regions
    gemm_bt<1><<<dim3(24, 64), 256, 0, stream>>>(query, qkv_w, qkv_b, d_out, 8192, 3072, 1024);
    // K2a: S = QK^T/32 + mask; E = exp(S) to attn region; row sums to ws
    attn_scores<<<dim3(16, 128), 256, 0, stream>>>(d_out, d_out + K_OFF, mask,
                                                   d_out + ATT_OFF, rowsum);
    // K2b: normalize attn in place + PV -> ctx
    attn_pv<<<dim3(16, 128), 256, 0, stream>>>(d_out + ATT_OFF, d_out + V_OFF, rowsum, ctx);
    // K3: out projection -> d_out[0:8M)
    gemm_bt<0><<<dim3(8, 64), 256, 0, stream>>>(ctx, out_w, out_b, d_out, 8192, 1024, 1024);
}